// Round 1
// baseline (516.917 us; speedup 1.0000x reference)
//
#include <hip/hip_runtime.h>
#include <hip/hip_bf16.h>

#define TPB 256
#define BM 32
#define NROW 32768
#define VV 1024
#define KD 256
#define TT 2048

#define LP_OFF 2L
#define ZQ_OFF (2L + 33554432L)
#define EM_OFF (33554434L + 8388608L)

// ws layout (floats)
#define WS_HIST 0
#define WS_CSUM 1024
#define WS_SSUM 2048
#define WS_MSUM 3072

__device__ __forceinline__ void gl_lds16(const float* g, float* l) {
  __builtin_amdgcn_global_load_lds(
      (const __attribute__((address_space(1))) void*)g,
      (__attribute__((address_space(3))) void*)l, 16, 0, 0);
}

__global__ __launch_bounds__(TPB) void tok_main(
    const float* __restrict__ z, const float* __restrict__ mask,
    const float* __restrict__ cw, float* __restrict__ out,
    float* __restrict__ ws) {
  __shared__ __align__(16) float z_s[BM][KD];      // 32 KB
  __shared__ __align__(16) float e_s[2][VV][4];    // 32 KB, e_s[k2][c][kk] = e[c][kc+4*k2+kk]
  __shared__ float mask_s[BM];
  __shared__ int argi_s[BM];
  __shared__ float cred[4], sred[4];

  const int tid = threadIdx.x;
  const int lane = tid & 63;
  const int wave = tid >> 6;
  const int n0 = blockIdx.x * BM;
  const float* e = cw + KD;  // skip codebook row 0

  // stage z tile: 32 rows x 1 KB, global_load_lds width-16
#pragma unroll
  for (int i = 0; i < 8; ++i) {
    int seg = wave * 8 + i;
    gl_lds16(&z[(size_t)(n0 + seg) * KD + lane * 4], &z_s[seg][0]);
  }
  if (tid < BM) mask_s[tid] = mask[n0 + tid];

  float acc[8][16];
#pragma unroll
  for (int r = 0; r < 8; ++r)
#pragma unroll
    for (int m = 0; m < 16; ++m) acc[r][m] = 0.f;

  for (int kc = 0; kc < KD; kc += 8) {
    __syncthreads();  // prior compute's e_s reads done before DMA overwrite
#pragma unroll
    for (int i = 0; i < 8; ++i) {
      int s = wave * 8 + i;
      int Wi = s >> 1, k2 = s & 1;       // rows grouped, k2 inner: L1-friendly
      int c = (Wi << 6) + lane;
      gl_lds16(&e[(size_t)c * KD + kc + (k2 << 2)], &e_s[k2][Wi << 6][0]);
    }
    __syncthreads();  // vmcnt(0) drain: e_s (and z_s on iter 0) ready
#pragma unroll
    for (int k2 = 0; k2 < 2; ++k2) {
      float4 zf[8];
#pragma unroll
      for (int rr = 0; rr < 8; ++rr)
        zf[rr] = *(const float4*)&z_s[(wave << 3) + rr][kc + (k2 << 2)];
#pragma unroll
      for (int m = 0; m < 16; ++m) {
        float4 ef = *(const float4*)&e_s[k2][(m << 6) + lane][0];
#pragma unroll
        for (int rr = 0; rr < 8; ++rr)
          acc[rr][m] += zf[rr].x * ef.x + zf[rr].y * ef.y +
                        zf[rr].z * ef.z + zf[rr].w * ef.w;
      }
    }
  }

  // ---- epilogue: per-row softmax stats, wave-local (wave owns 8 rows) ----
  const int rowbase = wave << 3;
#pragma unroll
  for (int rr = 0; rr < 8; ++rr) {
    float mv = acc[rr][0];
    int mc = lane;  // col = 0*64 + lane
#pragma unroll
    for (int m = 1; m < 16; ++m) {
      float v = acc[rr][m];
      int c = (m << 6) + lane;
      bool tk = v > mv;
      mc = tk ? c : mc;
      mv = tk ? v : mv;
    }
#pragma unroll
    for (int d = 32; d >= 1; d >>= 1) {
      float ov = __shfl_xor(mv, d);
      int oc = __shfl_xor(mc, d);
      bool tk = (ov > mv) || (ov == mv && oc < mc);  // first-index tiebreak
      mv = tk ? ov : mv;
      mc = tk ? oc : mc;
    }
    float sum = 0.f;
#pragma unroll
    for (int m = 0; m < 16; ++m) sum += __expf(acc[rr][m] - mv);
#pragma unroll
    for (int d = 32; d >= 1; d >>= 1) sum += __shfl_xor(sum, d);
    float lse = mv + __logf(sum);
    size_t base = LP_OFF + (size_t)(n0 + rowbase + rr) * VV;
#pragma unroll
    for (int m = 0; m < 16; ++m)
      out[base + (m << 6) + lane] = acc[rr][m] - lse;
    if (lane == 0) {
      argi_s[rowbase + rr] = mc;
      atomicAdd(&ws[WS_HIST + mc], mask_s[rowbase + rr]);  // mask=1.0 adds: exact
    }
  }
  __syncthreads();

  // ---- z_q gather + commitment + smoothness ----
  float csum = 0.f, ssum = 0.f;
  const bool has_prev = (n0 % TT) != 0;
#pragma unroll
  for (int i = 0; i < 8; ++i) {
    int q = i * TPB + tid;      // 0..2047 float4 slots
    int r = q >> 6;
    int c4 = (q & 63) << 2;
    int idx = argi_s[r];
    const float4 ev = *(const float4*)&e[(size_t)idx * KD + c4];
    const float4 zv = *(const float4*)&z_s[r][c4];
    *(float4*)&out[ZQ_OFF + (size_t)(n0 + r) * KD + c4] = ev;
    float mk = mask_s[r];
    float dx = zv.x - ev.x, dy = zv.y - ev.y, dz2 = zv.z - ev.z,
          dw = zv.w - ev.w;
    csum += mk * (dx * dx + dy * dy + dz2 * dz2 + dw * dw);
    if (r > 0) {
      const float4 pv = *(const float4*)&z_s[r - 1][c4];
      float ax = zv.x - pv.x, ay = zv.y - pv.y, az = zv.z - pv.z,
            aw = zv.w - pv.w;
      ssum += mk * (ax * ax + ay * ay + az * az + aw * aw);
    } else if (has_prev) {
      const float4 pv = *(const float4*)&z[(size_t)(n0 - 1) * KD + c4];
      float ax = zv.x - pv.x, ay = zv.y - pv.y, az = zv.z - pv.z,
            aw = zv.w - pv.w;
      ssum += mk * (ax * ax + ay * ay + az * az + aw * aw);
    }
  }
#pragma unroll
  for (int d = 32; d >= 1; d >>= 1) {
    csum += __shfl_xor(csum, d);
    ssum += __shfl_xor(ssum, d);
  }
  if (lane == 0) {
    cred[wave] = csum;
    sred[wave] = ssum;
  }
  __syncthreads();
  if (tid == 0) {
    ws[WS_CSUM + blockIdx.x] = cred[0] + cred[1] + cred[2] + cred[3];
    ws[WS_SSUM + blockIdx.x] = sred[0] + sred[1] + sred[2] + sred[3];
    float ms = 0.f;
    for (int r2 = 0; r2 < BM; ++r2) ms += mask_s[r2];
    ws[WS_MSUM + blockIdx.x] = ms;
  }
}

__global__ __launch_bounds__(1024) void tok_final(const float* __restrict__ ws,
                                                  float* __restrict__ out) {
  const int t = threadIdx.x;
  const int lane = t & 63, w = t >> 6;
  __shared__ float red[16];
  auto blockReduce = [&](float v) -> float {
#pragma unroll
    for (int d = 32; d >= 1; d >>= 1) v += __shfl_xor(v, d);
    __syncthreads();  // protect red reuse across calls
    if (lane == 0) red[w] = v;
    __syncthreads();
    float s = 0.f;
#pragma unroll
    for (int i = 0; i < 16; ++i) s += red[i];
    return s;
  };
  float Mtot = blockReduce(ws[WS_MSUM + t]);
  float Ctot = blockReduce(ws[WS_CSUM + t]);
  float Stot = blockReduce(ws[WS_SSUM + t]);
  float prob = ws[WS_HIST + t] / Mtot;
  float psum = blockReduce(prob);
  out[EM_OFF + t] = prob / psum;
  if (t == 0) {
    float vc = Mtot * (float)KD;
    out[0] = Stot / vc;   // smoothness_loss
    out[1] = Ctot / vc;   // commitment_loss
  }
}

extern "C" void kernel_launch(void* const* d_in, const int* in_sizes, int n_in,
                              void* d_out, int out_size, void* d_ws,
                              size_t ws_size, hipStream_t stream) {
  const float* z = (const float*)d_in[0];
  const float* mask = (const float*)d_in[1];
  const float* cw = (const float*)d_in[2];
  float* out = (float*)d_out;
  float* ws = (float*)d_ws;
  // zero the histogram region (rest of ws is overwritten every launch)
  hipMemsetAsync(ws, 0, 1024 * sizeof(float), stream);
  tok_main<<<NROW / BM, TPB, 0, stream>>>(z, mask, cw, out, ws);
  tok_final<<<1, 1024, 0, stream>>>(ws, out);
}

// Round 2
// 424.899 us; speedup vs baseline: 1.2166x; 1.2166x over previous
//
#include <hip/hip_runtime.h>
#include <hip/hip_bf16.h>

#define TPB 256
#define BM 32
#define NROW 32768
#define VV 1024
#define KD 256
#define TT 2048
#define NCH 64  // K chunks of 4 floats

#define LP_OFF 2L
#define ZQ_OFF (2L + 33554432L)
#define EM_OFF (33554434L + 8388608L)

// ws layout (floats)
#define WS_HIST 0
#define WS_CSUM 1024
#define WS_SSUM 2048
#define WS_MSUM 3072
#define WS_EP 4096  // transposed e: [64 chunks][1024 cols][4 k] = 262144 floats
#define WS_NEED (((size_t)WS_EP + (size_t)NCH * VV * 4) * sizeof(float))

__device__ __forceinline__ void gl_lds16(const float* g, float* l) {
  __builtin_amdgcn_global_load_lds(
      (const __attribute__((address_space(1))) void*)g,
      (__attribute__((address_space(3))) void*)l, 16, 0, 0);
}

// e_p[ch][c][j] = e[c][ch*4+j]; coalesced writes, strided (L2-resident) reads.
__global__ __launch_bounds__(256) void tok_transpose(
    const float* __restrict__ cw, float* __restrict__ ep) {
  int t = blockIdx.x * 256 + threadIdx.x;  // 65536
  int ch = t >> 10, c = t & 1023;
  const float4 v = *(const float4*)&cw[(size_t)(1 + c) * KD + (ch << 2)];
  *(float4*)&ep[(size_t)((ch << 10) + c) << 2] = v;
}

template <bool EP>
__global__ __launch_bounds__(TPB) void tok_main(
    const float* __restrict__ z, const float* __restrict__ mask,
    const float* __restrict__ cw, const float* __restrict__ ep,
    float* __restrict__ out, float* __restrict__ ws) {
  __shared__ __align__(16) float z_s[BM][KD];    // 32 KB
  __shared__ __align__(16) float e_s[2][VV][4];  // 2 x 16 KB double buffer
  __shared__ int argi_s[BM];
  __shared__ float cred[4], sred[4];

  const int tid = threadIdx.x;
  const int lane = tid & 63;
  const int wave = tid >> 6;
  const int n0 = blockIdx.x * BM;
  const float* e = cw + KD;  // skip codebook row 0

  // ---- prologue: stage z tile (8 DMA/wave), then chunk 0 (4 DMA/wave) ----
#pragma unroll
  for (int i = 0; i < 8; ++i) {
    int seg = wave * 8 + i;
    gl_lds16(&z[(size_t)(n0 + seg) * KD + lane * 4], &z_s[seg][0]);
  }

  auto issue_chunk = [&](int j, int b) {
#pragma unroll
    for (int l = 0; l < 4; ++l) {
      const int s = (wave << 2) + l;  // 16 segments of 64 cols
      const float* src;
      if constexpr (EP)
        src = ep + ((size_t)j << 12) + (s << 8) + (lane << 2);
      else
        src = e + (size_t)((s << 6) + lane) * KD + (j << 2);
      gl_lds16(src, &e_s[b][s << 6][0]);
    }
  };

  issue_chunk(0, 0);

  float acc[8][16];
#pragma unroll
  for (int r = 0; r < 8; ++r)
#pragma unroll
    for (int m = 0; m < 16; ++m) acc[r][m] = 0.f;

  auto compute = [&](int i) {
    const int kb = i << 2;
    const int b = i & 1;
    float4 zf[8];
#pragma unroll
    for (int rr = 0; rr < 8; ++rr)
      zf[rr] = *(const float4*)&z_s[(wave << 3) + rr][kb];
#pragma unroll
    for (int m = 0; m < 16; ++m) {
      float4 ef = *(const float4*)&e_s[b][(m << 6) + lane][0];
#pragma unroll
      for (int rr = 0; rr < 8; ++rr)
        acc[rr][m] += zf[rr].x * ef.x + zf[rr].y * ef.y + zf[rr].z * ef.z +
                      zf[rr].w * ef.w;
    }
  };

  // ---- pipelined main loop: prefetch i+1 while computing i ----
  for (int i = 0; i < NCH - 1; ++i) {
    asm volatile("" ::: "memory");  // fence: no ds_read sinks below DMA issue
    issue_chunk(i + 1, (i + 1) & 1);
    asm volatile("s_waitcnt vmcnt(4)" ::: "memory");  // chunk i (and z) done
    __builtin_amdgcn_s_barrier();  // all waves' chunk-i DMA visible
    compute(i);
    __builtin_amdgcn_s_barrier();  // all reads of buf[i&1] done before reuse
  }
  asm volatile("s_waitcnt vmcnt(0)" ::: "memory");
  __builtin_amdgcn_s_barrier();
  compute(NCH - 1);

  // ---- epilogue: per-row softmax stats, wave-local (wave owns 8 rows) ----
  const int rowbase = wave << 3;
#pragma unroll
  for (int rr = 0; rr < 8; ++rr) {
    float mv = acc[rr][0];
    int mc = lane;
#pragma unroll
    for (int m = 1; m < 16; ++m) {
      float v = acc[rr][m];
      int c = (m << 6) + lane;
      bool tk = v > mv;
      mc = tk ? c : mc;
      mv = tk ? v : mv;
    }
#pragma unroll
    for (int d = 32; d >= 1; d >>= 1) {
      float ov = __shfl_xor(mv, d);
      int oc = __shfl_xor(mc, d);
      bool tk = (ov > mv) || (ov == mv && oc < mc);  // first-index tiebreak
      mv = tk ? ov : mv;
      mc = tk ? oc : mc;
    }
    float sum = 0.f;
#pragma unroll
    for (int m = 0; m < 16; ++m) sum += __expf(acc[rr][m] - mv);
#pragma unroll
    for (int d = 32; d >= 1; d >>= 1) sum += __shfl_xor(sum, d);
    float lse = mv + __logf(sum);
    size_t base = LP_OFF + (size_t)(n0 + rowbase + rr) * VV;
#pragma unroll
    for (int m = 0; m < 16; ++m)
      out[base + (m << 6) + lane] = acc[rr][m] - lse;
    if (lane == 0) {
      argi_s[rowbase + rr] = mc;
      atomicAdd(&ws[WS_HIST + mc], mask[n0 + rowbase + rr]);  // 1.0 adds: exact
    }
  }
  __syncthreads();

  // ---- z_q gather + commitment + smoothness ----
  float csum = 0.f, ssum = 0.f;
  const bool has_prev = (n0 % TT) != 0;
#pragma unroll
  for (int i = 0; i < 8; ++i) {
    int q = i * TPB + tid;  // 0..2047 float4 slots
    int r = q >> 6;
    int c4 = (q & 63) << 2;
    int idx = argi_s[r];
    const float4 ev = *(const float4*)&e[(size_t)idx * KD + c4];
    const float4 zv = *(const float4*)&z_s[r][c4];
    *(float4*)&out[ZQ_OFF + (size_t)(n0 + r) * KD + c4] = ev;
    float mk = mask[n0 + r];
    float dx = zv.x - ev.x, dy = zv.y - ev.y, dz2 = zv.z - ev.z,
          dw = zv.w - ev.w;
    csum += mk * (dx * dx + dy * dy + dz2 * dz2 + dw * dw);
    if (r > 0) {
      const float4 pv = *(const float4*)&z_s[r - 1][c4];
      float ax = zv.x - pv.x, ay = zv.y - pv.y, az = zv.z - pv.z,
            aw = zv.w - pv.w;
      ssum += mk * (ax * ax + ay * ay + az * az + aw * aw);
    } else if (has_prev) {
      const float4 pv = *(const float4*)&z[(size_t)(n0 - 1) * KD + c4];
      float ax = zv.x - pv.x, ay = zv.y - pv.y, az = zv.z - pv.z,
            aw = zv.w - pv.w;
      ssum += mk * (ax * ax + ay * ay + az * az + aw * aw);
    }
  }
#pragma unroll
  for (int d = 32; d >= 1; d >>= 1) {
    csum += __shfl_xor(csum, d);
    ssum += __shfl_xor(ssum, d);
  }
  if (lane == 0) {
    cred[wave] = csum;
    sred[wave] = ssum;
  }
  __syncthreads();
  if (tid == 0) {
    ws[WS_CSUM + blockIdx.x] = cred[0] + cred[1] + cred[2] + cred[3];
    ws[WS_SSUM + blockIdx.x] = sred[0] + sred[1] + sred[2] + sred[3];
    float ms = 0.f;
    for (int r2 = 0; r2 < BM; ++r2) ms += mask[n0 + r2];
    ws[WS_MSUM + blockIdx.x] = ms;
  }
}

__global__ __launch_bounds__(1024) void tok_final(const float* __restrict__ ws,
                                                  float* __restrict__ out) {
  const int t = threadIdx.x;
  const int lane = t & 63, w = t >> 6;
  __shared__ float red[16];
  auto blockReduce = [&](float v) -> float {
#pragma unroll
    for (int d = 32; d >= 1; d >>= 1) v += __shfl_xor(v, d);
    __syncthreads();
    if (lane == 0) red[w] = v;
    __syncthreads();
    float s = 0.f;
#pragma unroll
    for (int i = 0; i < 16; ++i) s += red[i];
    return s;
  };
  float Mtot = blockReduce(ws[WS_MSUM + t]);
  float Ctot = blockReduce(ws[WS_CSUM + t]);
  float Stot = blockReduce(ws[WS_SSUM + t]);
  float prob = ws[WS_HIST + t] / Mtot;
  float psum = blockReduce(prob);
  out[EM_OFF + t] = prob / psum;
  if (t == 0) {
    float vc = Mtot * (float)KD;
    out[0] = Stot / vc;  // smoothness_loss
    out[1] = Ctot / vc;  // commitment_loss
  }
}

extern "C" void kernel_launch(void* const* d_in, const int* in_sizes, int n_in,
                              void* d_out, int out_size, void* d_ws,
                              size_t ws_size, hipStream_t stream) {
  const float* z = (const float*)d_in[0];
  const float* mask = (const float*)d_in[1];
  const float* cw = (const float*)d_in[2];
  float* out = (float*)d_out;
  float* ws = (float*)d_ws;
  hipMemsetAsync(ws, 0, 1024 * sizeof(float), stream);  // histogram zeros
  if (ws_size >= WS_NEED) {
    tok_transpose<<<256, 256, 0, stream>>>(cw, ws + WS_EP);
    tok_main<true><<<NROW / BM, TPB, 0, stream>>>(z, mask, cw, ws + WS_EP, out,
                                                  ws);
  } else {
    tok_main<false><<<NROW / BM, TPB, 0, stream>>>(z, mask, cw, nullptr, out,
                                                   ws);
  }
  tok_final<<<1, 1024, 0, stream>>>(ws, out);
}

// Round 3
// 412.236 us; speedup vs baseline: 1.2539x; 1.0307x over previous
//
#include <hip/hip_runtime.h>
#include <hip/hip_bf16.h>

#define TPB 256
#define BM 32
#define NROW 32768
#define VV 1024
#define KD 256
#define TT 2048
#define NCH 64  // K chunks of 4 floats

#define LP_OFF 2L
#define ZQ_OFF (2L + 33554432L)
#define EM_OFF (33554434L + 8388608L)

// ws layout (floats)
#define WS_HIST 0
#define WS_CSUM 1024
#define WS_SSUM 2048
#define WS_MSUM 3072
#define WS_EP 4096  // transposed e: [64 chunks][1024 cols][4 k] = 262144 floats
#define WS_NEED (((size_t)WS_EP + (size_t)NCH * VV * 4) * sizeof(float))

__device__ __forceinline__ void gl_lds16(const float* g, float* l) {
  __builtin_amdgcn_global_load_lds(
      (const __attribute__((address_space(1))) void*)g,
      (__attribute__((address_space(3))) void*)l, 16, 0, 0);
}

// e_p[ch][c][j] = e[c][ch*4+j]; coalesced writes, strided (L2-resident) reads.
__global__ __launch_bounds__(256) void tok_transpose(
    const float* __restrict__ cw, float* __restrict__ ep) {
  int t = blockIdx.x * 256 + threadIdx.x;  // 65536
  int ch = t >> 10, c = t & 1023;
  const float4 v = *(const float4*)&cw[(size_t)(1 + c) * KD + (ch << 2)];
  *(float4*)&ep[(size_t)((ch << 10) + c) << 2] = v;
}

template <bool EPATH>
__global__ __launch_bounds__(TPB, 2) void tok_main(
    const float* __restrict__ z, const float* __restrict__ mask,
    const float* __restrict__ cw, const float* __restrict__ ep,
    float* __restrict__ out, float* __restrict__ ws) {
  __shared__ __align__(16) float z_s[BM][KD];  // 32 KB (only LDS tile)
  __shared__ int argi_s[BM];
  __shared__ float cred[4], sred[4];

  const int tid = threadIdx.x;
  const int lane = tid & 63;
  const int wave = tid >> 6;
  const int n0 = blockIdx.x * BM;
  const float* e = cw + KD;  // skip codebook row 0

  // ---- stage z tile to LDS (8 DMA/wave, width-16), then full drain ----
#pragma unroll
  for (int i = 0; i < 8; ++i) {
    int seg = wave * 8 + i;
    gl_lds16(&z[(size_t)(n0 + seg) * KD + lane * 4], &z_s[seg][0]);
  }
  __syncthreads();  // compiler emits vmcnt(0) drain before s_barrier

  float acc[8][16];
#pragma unroll
  for (int r = 0; r < 8; ++r)
#pragma unroll
    for (int m = 0; m < 16; ++m) acc[r][m] = 0.f;

  // ---- main loop: e chunk global(L2)->regs, z from LDS broadcast ----
#pragma unroll 1
  for (int i = 0; i < NCH; ++i) {
    float4 ef[16];
#pragma unroll
    for (int m = 0; m < 16; ++m) {
      if constexpr (EPATH)
        ef[m] = *(const float4*)&ep[(((size_t)i << 10) + (m << 6) + lane) << 2];
      else
        ef[m] = *(const float4*)&e[(size_t)((m << 6) + lane) * KD + (i << 2)];
    }
    float4 zf[8];
#pragma unroll
    for (int rr = 0; rr < 8; ++rr)
      zf[rr] = *(const float4*)&z_s[(wave << 3) + rr][i << 2];  // broadcast
#pragma unroll
    for (int m = 0; m < 16; ++m)
#pragma unroll
      for (int rr = 0; rr < 8; ++rr)
        acc[rr][m] += zf[rr].x * ef[m].x + zf[rr].y * ef[m].y +
                      zf[rr].z * ef[m].z + zf[rr].w * ef[m].w;
  }

  // ---- epilogue: per-row softmax stats, wave-local (wave owns 8 rows) ----
  const int rowbase = wave << 3;
#pragma unroll
  for (int rr = 0; rr < 8; ++rr) {
    float mv = acc[rr][0];
    int mc = lane;
#pragma unroll
    for (int m = 1; m < 16; ++m) {
      float v = acc[rr][m];
      int c = (m << 6) + lane;
      bool tk = v > mv;
      mc = tk ? c : mc;
      mv = tk ? v : mv;
    }
#pragma unroll
    for (int d = 32; d >= 1; d >>= 1) {
      float ov = __shfl_xor(mv, d);
      int oc = __shfl_xor(mc, d);
      bool tk = (ov > mv) || (ov == mv && oc < mc);  // first-index tiebreak
      mv = tk ? ov : mv;
      mc = tk ? oc : mc;
    }
    float sum = 0.f;
#pragma unroll
    for (int m = 0; m < 16; ++m) sum += __expf(acc[rr][m] - mv);
#pragma unroll
    for (int d = 32; d >= 1; d >>= 1) sum += __shfl_xor(sum, d);
    float lse = mv + __logf(sum);
    size_t base = LP_OFF + (size_t)(n0 + rowbase + rr) * VV;
#pragma unroll
    for (int m = 0; m < 16; ++m)
      out[base + (m << 6) + lane] = acc[rr][m] - lse;
    if (lane == 0) {
      argi_s[rowbase + rr] = mc;
      atomicAdd(&ws[WS_HIST + mc], mask[n0 + rowbase + rr]);  // 1.0 adds: exact
    }
  }
  __syncthreads();

  // ---- z_q gather + commitment + smoothness ----
  float csum = 0.f, ssum = 0.f;
  const bool has_prev = (n0 % TT) != 0;
#pragma unroll
  for (int i = 0; i < 8; ++i) {
    int q = i * TPB + tid;  // 0..2047 float4 slots
    int r = q >> 6;
    int c4 = (q & 63) << 2;
    int idx = argi_s[r];
    const float4 ev = *(const float4*)&e[(size_t)idx * KD + c4];
    const float4 zv = *(const float4*)&z_s[r][c4];
    *(float4*)&out[ZQ_OFF + (size_t)(n0 + r) * KD + c4] = ev;
    float mk = mask[n0 + r];
    float dx = zv.x - ev.x, dy = zv.y - ev.y, dz2 = zv.z - ev.z,
          dw = zv.w - ev.w;
    csum += mk * (dx * dx + dy * dy + dz2 * dz2 + dw * dw);
    if (r > 0) {
      const float4 pv = *(const float4*)&z_s[r - 1][c4];
      float ax = zv.x - pv.x, ay = zv.y - pv.y, az = zv.z - pv.z,
            aw = zv.w - pv.w;
      ssum += mk * (ax * ax + ay * ay + az * az + aw * aw);
    } else if (has_prev) {
      const float4 pv = *(const float4*)&z[(size_t)(n0 - 1) * KD + c4];
      float ax = zv.x - pv.x, ay = zv.y - pv.y, az = zv.z - pv.z,
            aw = zv.w - pv.w;
      ssum += mk * (ax * ax + ay * ay + az * az + aw * aw);
    }
  }
#pragma unroll
  for (int d = 32; d >= 1; d >>= 1) {
    csum += __shfl_xor(csum, d);
    ssum += __shfl_xor(ssum, d);
  }
  if (lane == 0) {
    cred[wave] = csum;
    sred[wave] = ssum;
  }
  __syncthreads();
  if (tid == 0) {
    ws[WS_CSUM + blockIdx.x] = cred[0] + cred[1] + cred[2] + cred[3];
    ws[WS_SSUM + blockIdx.x] = sred[0] + sred[1] + sred[2] + sred[3];
    float ms = 0.f;
    for (int r2 = 0; r2 < BM; ++r2) ms += mask[n0 + r2];
    ws[WS_MSUM + blockIdx.x] = ms;
  }
}

__global__ __launch_bounds__(1024) void tok_final(const float* __restrict__ ws,
                                                  float* __restrict__ out) {
  const int t = threadIdx.x;
  const int lane = t & 63, w = t >> 6;
  __shared__ float red[16];
  auto blockReduce = [&](float v) -> float {
#pragma unroll
    for (int d = 32; d >= 1; d >>= 1) v += __shfl_xor(v, d);
    __syncthreads();
    if (lane == 0) red[w] = v;
    __syncthreads();
    float s = 0.f;
#pragma unroll
    for (int i = 0; i < 16; ++i) s += red[i];
    return s;
  };
  float Mtot = blockReduce(ws[WS_MSUM + t]);
  float Ctot = blockReduce(ws[WS_CSUM + t]);
  float Stot = blockReduce(ws[WS_SSUM + t]);
  float prob = ws[WS_HIST + t] / Mtot;
  float psum = blockReduce(prob);
  out[EM_OFF + t] = prob / psum;
  if (t == 0) {
    float vc = Mtot * (float)KD;
    out[0] = Stot / vc;  // smoothness_loss
    out[1] = Ctot / vc;  // commitment_loss
  }
}

extern "C" void kernel_launch(void* const* d_in, const int* in_sizes, int n_in,
                              void* d_out, int out_size, void* d_ws,
                              size_t ws_size, hipStream_t stream) {
  const float* z = (const float*)d_in[0];
  const float* mask = (const float*)d_in[1];
  const float* cw = (const float*)d_in[2];
  float* out = (float*)d_out;
  float* ws = (float*)d_ws;
  hipMemsetAsync(ws, 0, 1024 * sizeof(float), stream);  // histogram zeros
  if (ws_size >= WS_NEED) {
    tok_transpose<<<256, 256, 0, stream>>>(cw, ws + WS_EP);
    tok_main<true><<<NROW / BM, TPB, 0, stream>>>(z, mask, cw, ws + WS_EP, out,
                                                  ws);
  } else {
    tok_main<false><<<NROW / BM, TPB, 0, stream>>>(z, mask, cw, nullptr, out,
                                                   ws);
  }
  tok_final<<<1, 1024, 0, stream>>>(ws, out);
}

// Round 4
// 103.507 us; speedup vs baseline: 4.9940x; 3.9827x over previous
//
#include <hip/hip_runtime.h>
#include <hip/hip_bf16.h>

#define TPB 256
#define TPB2 512
#define BM 32
#define NROW 32768
#define NBLK (NROW / BM)
#define VV 1024
#define KD 256
#define TT 2048

#define LP_OFF 2L
#define ZQ_OFF (2L + 33554432L)
#define EM_OFF (33554434L + 8388608L)

// ws layout (floats)
#define WS_HIST 0
#define WS_CSUM 1024
#define WS_SSUM 2048
#define WS_MSUM 3072
#define WS_E8 4096  // bf16 e in k-oct planes: [32 octs][1024 n][8] = 512 KB
#define WS_NEED (4096 * 4 + 32 * 1024 * 8 * 2)

typedef __attribute__((ext_vector_type(8))) short bf16x8;
typedef __attribute__((ext_vector_type(4))) float f32x4;

__device__ __forceinline__ void gl_lds16(const float* g, float* l) {
  __builtin_amdgcn_global_load_lds(
      (const __attribute__((address_space(1))) void*)g,
      (__attribute__((address_space(3))) void*)l, 16, 0, 0);
}

__device__ __forceinline__ unsigned short f2bf(float x) {  // RNE
  unsigned u = __float_as_uint(x);
  unsigned r = ((u >> 16) & 1u) + 0x7FFFu;
  return (unsigned short)((u + r) >> 16);
}

// e8[o][n][j] = bf16(e[n][8o+j]); write-coalesced, reads scattered (1 MB, L2)
__global__ __launch_bounds__(256) void tok_prep(const float* __restrict__ cw,
                                                unsigned short* __restrict__ e8) {
  int t = blockIdx.x * 256 + threadIdx.x;  // 32768
  int o = t >> 10, n = t & 1023;
  const float* src = cw + (size_t)(1 + n) * KD + (o << 3);
  float4 a = *(const float4*)src;
  float4 b = *(const float4*)(src + 4);
  int4 pk;
  pk.x = f2bf(a.x) | ((unsigned)f2bf(a.y) << 16);
  pk.y = f2bf(a.z) | ((unsigned)f2bf(a.w) << 16);
  pk.z = f2bf(b.x) | ((unsigned)f2bf(b.y) << 16);
  pk.w = f2bf(b.z) | ((unsigned)f2bf(b.w) << 16);
  *(int4*)(e8 + (((size_t)(o << 10) + n) << 3)) = pk;
}

__global__ __launch_bounds__(TPB2, 2) void tok_mfma(
    const float* __restrict__ z, const float* __restrict__ mask,
    const float* __restrict__ cw, const unsigned short* __restrict__ e8,
    float* __restrict__ out, float* __restrict__ ws) {
  __shared__ __align__(16) float z_s[BM][KD];            // 32 KB fp32
  __shared__ __align__(16) unsigned short z8[32][32][8]; // [oct][row][8] 16 KB
  __shared__ unsigned wkey[32][8][4];                    // per-row/wave top4 keys
  __shared__ float wmax[32][8];
  __shared__ float wsum[32][8];
  __shared__ float exv[32][4];
  __shared__ int exi[32][4];
  __shared__ int argi[32];
  __shared__ float cred[8], sred[8];

  const int tid = threadIdx.x;
  const int lane = tid & 63;
  const int w = tid >> 6;     // wave 0..7
  const int g = lane >> 4;    // k-group 0..3
  const int lm = lane & 15;
  const int c0 = w << 7;      // wave's 128-col base
  const int n0 = blockIdx.x * BM;

  // ---- stage z fp32 -> LDS (wave-uniform base + lane*16) ----
#pragma unroll
  for (int i = 0; i < 4; ++i) {
    int row = (i << 3) + w;
    gl_lds16(&z[(size_t)(n0 + row) * KD + (lane << 2)], &z_s[row][lane << 2]);
  }
  __syncthreads();
  // ---- convert to bf16 oct-plane layout ----
#pragma unroll
  for (int i = 0; i < 2; ++i) {
    int e = (i << 9) + tid;
    int o = e >> 5, r = e & 31;
    float4 a = *(const float4*)&z_s[r][o << 3];
    float4 b = *(const float4*)&z_s[r][(o << 3) + 4];
    int4 pk;
    pk.x = f2bf(a.x) | ((unsigned)f2bf(a.y) << 16);
    pk.y = f2bf(a.z) | ((unsigned)f2bf(a.w) << 16);
    pk.z = f2bf(b.x) | ((unsigned)f2bf(b.y) << 16);
    pk.w = f2bf(b.z) | ((unsigned)f2bf(b.w) << 16);
    *(int4*)&z8[o][r][0] = pk;
  }
  __syncthreads();

  // ---- MFMA main loop: A from LDS, B from global (L2), no barriers ----
  const bf16x8* za = (const bf16x8*)&z8[0][0][0];
  const bf16x8* bb = (const bf16x8*)e8 + (g << 10) + c0 + lm;
  f32x4 accA[8], accB[8];
  const f32x4 zz = {0.f, 0.f, 0.f, 0.f};
#pragma unroll
  for (int nt = 0; nt < 8; ++nt) { accA[nt] = zz; accB[nt] = zz; }
#pragma unroll 2
  for (int step = 0; step < 8; ++step) {
    bf16x8 a0 = za[(step << 7) + (g << 5) + lm];
    bf16x8 a1 = za[(step << 7) + (g << 5) + 16 + lm];
#pragma unroll
    for (int nt = 0; nt < 8; ++nt) {
      bf16x8 bv = bb[(step << 12) + (nt << 4)];
      accA[nt] = __builtin_amdgcn_mfma_f32_16x16x32_bf16(a0, bv, accA[nt], 0, 0, 0);
      accB[nt] = __builtin_amdgcn_mfma_f32_16x16x32_bf16(a1, bv, accB[nt], 0, 0, 0);
    }
  }

  // D layout: row = mt*16 + 4*g + j, col = c0 + nt*16 + lm   (m89-verified)
  // ---- E1: wave-local row max + packed top-4 keys ----
  auto phase1 = [&](f32x4(&ac)[8], int mt) {
#pragma unroll
    for (int j = 0; j < 4; ++j) {
      int r = (mt << 4) + (g << 2) + j;
      float mv = -3.4e38f;
      unsigned cur[8];
#pragma unroll
      for (int nt = 0; nt < 8; ++nt) {
        float v = ac[nt][j];
        mv = fmaxf(mv, v);
        unsigned b = __float_as_uint(v);
        b ^= (unsigned)((int)b >> 31) | 0x80000000u;
        cur[nt] = (b & 0xFFFFFC00u) |
                  (1023u - (unsigned)(c0 + (nt << 4) + lm));
      }
#pragma unroll
      for (int d = 1; d <= 8; d <<= 1) mv = fmaxf(mv, __shfl_xor(mv, d));
      if (lm == 0) wmax[r][w] = mv;
#pragma unroll
      for (int t2 = 0; t2 < 4; ++t2) {
        unsigned mk = cur[0];
#pragma unroll
        for (int nt = 1; nt < 8; ++nt) mk = mk > cur[nt] ? mk : cur[nt];
#pragma unroll
        for (int d = 1; d <= 8; d <<= 1) {
          unsigned o2 = __shfl_xor(mk, d);
          mk = mk > o2 ? mk : o2;
        }
        if (lm == 0) wkey[r][w][t2] = mk;
#pragma unroll
        for (int nt = 0; nt < 8; ++nt)
          if (cur[nt] == mk) cur[nt] = 0;
      }
    }
  };
  phase1(accA, 0);
  phase1(accB, 1);
  __syncthreads();

  // ---- E2: exp partial sums vs global comp max ----
  auto phase2 = [&](f32x4(&ac)[8], int mt) {
#pragma unroll
    for (int j = 0; j < 4; ++j) {
      int r = (mt << 4) + (g << 2) + j;
      float M = wmax[r][0];
#pragma unroll
      for (int w2 = 1; w2 < 8; ++w2) M = fmaxf(M, wmax[r][w2]);
      float s = 0.f;
#pragma unroll
      for (int nt = 0; nt < 8; ++nt) s += __expf(ac[nt][j] - M);
#pragma unroll
      for (int d = 1; d <= 8; d <<= 1) s += __shfl_xor(s, d);
      if (lm == 0) wsum[r][w] = s;
    }
  };
  phase2(accA, 0);
  phase2(accB, 1);
  __syncthreads();

  // ---- E3: lse + log_probs store ----
  auto phase3 = [&](f32x4(&ac)[8], int mt) {
#pragma unroll
    for (int j = 0; j < 4; ++j) {
      int r = (mt << 4) + (g << 2) + j;
      float M = wmax[r][0];
#pragma unroll
      for (int w2 = 1; w2 < 8; ++w2) M = fmaxf(M, wmax[r][w2]);
      float S = 0.f;
#pragma unroll
      for (int w2 = 0; w2 < 8; ++w2) S += wsum[r][w2];
      float lse = M + __logf(S);
      size_t base = LP_OFF + (size_t)(n0 + r) * VV;
#pragma unroll
      for (int nt = 0; nt < 8; ++nt)
        out[base + c0 + (nt << 4) + lm] = ac[nt][j] - lse;
    }
  };
  phase3(accA, 0);
  phase3(accB, 1);

  // ---- E4A: global comp top-4 per row (wave w owns rows 4w..4w+3) ----
  const int r4 = w << 2;
#pragma unroll
  for (int rr = 0; rr < 4; ++rr) {
    int row = r4 + rr;
    unsigned key = (lane < 32) ? wkey[row][lane >> 2][lane & 3] : 0u;
#pragma unroll
    for (int t2 = 0; t2 < 4; ++t2) {
      unsigned mk = key;
#pragma unroll
      for (int d = 1; d <= 32; d <<= 1) {
        unsigned o2 = __shfl_xor(mk, d);
        mk = mk > o2 ? mk : o2;
      }
      exi[row][t2] = (int)(1023u - (mk & 0x3FFu));  // wave-uniform value
      if (key == mk) key = 0;
    }
  }
  // ---- E4B: exact fp32 dots for 4 candidates x 4 rows per wave ----
#pragma unroll
  for (int p = 0; p < 2; ++p) {
    int row = r4 + (p << 1) + (lane >> 5);
    int cd = (lane >> 3) & 3;
    int cand = exi[row][cd];
    int seg = lane & 7;
    const float* er = cw + (size_t)(1 + cand) * KD + (seg << 5);
    const float* zr = &z_s[row][seg << 5];
    float s = 0.f;
#pragma unroll
    for (int i2 = 0; i2 < 8; ++i2) {
      float4 a4 = *(const float4*)(zr + (i2 << 2));
      float4 b4 = *(const float4*)(er + (i2 << 2));
      s += a4.x * b4.x + a4.y * b4.y + a4.z * b4.z + a4.w * b4.w;
    }
    s += __shfl_xor(s, 1);
    s += __shfl_xor(s, 2);
    s += __shfl_xor(s, 4);
    if (seg == 0) exv[row][cd] = s;
  }
  __syncthreads();
  // ---- select final argmax (exact values, first-index tiebreak) ----
  if (tid < 32) {
    int row = tid;
    float bv = exv[row][0];
    int bi = exi[row][0];
#pragma unroll
    for (int c = 1; c < 4; ++c) {
      float v = exv[row][c];
      int ci = exi[row][c];
      if (v > bv || (v == bv && ci < bi)) { bv = v; bi = ci; }
    }
    argi[row] = bi;
    atomicAdd(&ws[WS_HIST + bi], mask[n0 + row]);  // mask=1.0 adds: exact
  }
  __syncthreads();

  // ---- E5: z_q gather + commitment + smoothness ----
  float csum = 0.f, ssum = 0.f;
  const bool has_prev = (n0 % TT) != 0;
#pragma unroll
  for (int i = 0; i < 4; ++i) {
    int q = i * TPB2 + tid;  // 0..2047 float4 slots
    int r = q >> 6;
    int c4 = (q & 63) << 2;
    int idx = argi[r];
    const float4 ev = *(const float4*)&cw[(size_t)(1 + idx) * KD + c4];
    const float4 zv = *(const float4*)&z_s[r][c4];
    *(float4*)&out[ZQ_OFF + (size_t)(n0 + r) * KD + c4] = ev;
    float mk = mask[n0 + r];
    float dx = zv.x - ev.x, dy = zv.y - ev.y, dz2 = zv.z - ev.z,
          dw = zv.w - ev.w;
    csum += mk * (dx * dx + dy * dy + dz2 * dz2 + dw * dw);
    if (r > 0) {
      const float4 pv = *(const float4*)&z_s[r - 1][c4];
      float ax = zv.x - pv.x, ay = zv.y - pv.y, az = zv.z - pv.z,
            aw = zv.w - pv.w;
      ssum += mk * (ax * ax + ay * ay + az * az + aw * aw);
    } else if (has_prev) {
      const float4 pv = *(const float4*)&z[(size_t)(n0 - 1) * KD + c4];
      float ax = zv.x - pv.x, ay = zv.y - pv.y, az = zv.z - pv.z,
            aw = zv.w - pv.w;
      ssum += mk * (ax * ax + ay * ay + az * az + aw * aw);
    }
  }
#pragma unroll
  for (int d = 1; d <= 32; d <<= 1) {
    csum += __shfl_xor(csum, d);
    ssum += __shfl_xor(ssum, d);
  }
  if (lane == 0) { cred[w] = csum; sred[w] = ssum; }
  __syncthreads();
  if (tid == 0) {
    float cs = 0.f, ss2 = 0.f;
#pragma unroll
    for (int i = 0; i < 8; ++i) { cs += cred[i]; ss2 += sred[i]; }
    ws[WS_CSUM + blockIdx.x] = cs;
    ws[WS_SSUM + blockIdx.x] = ss2;
    float ms = 0.f;
    for (int r2 = 0; r2 < BM; ++r2) ms += mask[n0 + r2];
    ws[WS_MSUM + blockIdx.x] = ms;
  }
}

// ---------- fallback (R3 fp32 path) if ws too small ----------
__global__ __launch_bounds__(TPB, 2) void tok_fb(
    const float* __restrict__ z, const float* __restrict__ mask,
    const float* __restrict__ cw, float* __restrict__ out,
    float* __restrict__ ws) {
  __shared__ __align__(16) float z_s[BM][KD];
  __shared__ int argi_s[BM];
  __shared__ float cred[4], sred[4];
  const int tid = threadIdx.x;
  const int lane = tid & 63;
  const int wave = tid >> 6;
  const int n0 = blockIdx.x * BM;
  const float* e = cw + KD;
#pragma unroll
  for (int i = 0; i < 8; ++i) {
    int seg = wave * 8 + i;
    gl_lds16(&z[(size_t)(n0 + seg) * KD + lane * 4], &z_s[seg][0]);
  }
  __syncthreads();
  float acc[8][16];
#pragma unroll
  for (int r = 0; r < 8; ++r)
#pragma unroll
    for (int m = 0; m < 16; ++m) acc[r][m] = 0.f;
#pragma unroll 1
  for (int i = 0; i < 64; ++i) {
    float4 ef[16];
#pragma unroll
    for (int m = 0; m < 16; ++m)
      ef[m] = *(const float4*)&e[(size_t)((m << 6) + lane) * KD + (i << 2)];
    float4 zf[8];
#pragma unroll
    for (int rr = 0; rr < 8; ++rr)
      zf[rr] = *(const float4*)&z_s[(wave << 3) + rr][i << 2];
#pragma unroll
    for (int m = 0; m < 16; ++m)
#pragma unroll
      for (int rr = 0; rr < 8; ++rr)
        acc[rr][m] += zf[rr].x * ef[m].x + zf[rr].y * ef[m].y +
                      zf[rr].z * ef[m].z + zf[rr].w * ef[m].w;
  }
  const int rowbase = wave << 3;
#pragma unroll
  for (int rr = 0; rr < 8; ++rr) {
    float mv = acc[rr][0];
    int mc = lane;
#pragma unroll
    for (int m = 1; m < 16; ++m) {
      float v = acc[rr][m];
      int c = (m << 6) + lane;
      bool tk = v > mv;
      mc = tk ? c : mc;
      mv = tk ? v : mv;
    }
#pragma unroll
    for (int d = 32; d >= 1; d >>= 1) {
      float ov = __shfl_xor(mv, d);
      int oc = __shfl_xor(mc, d);
      bool tk = (ov > mv) || (ov == mv && oc < mc);
      mv = tk ? ov : mv;
      mc = tk ? oc : mc;
    }
    float sum = 0.f;
#pragma unroll
    for (int m = 0; m < 16; ++m) sum += __expf(acc[rr][m] - mv);
#pragma unroll
    for (int d = 32; d >= 1; d >>= 1) sum += __shfl_xor(sum, d);
    float lse = mv + __logf(sum);
    size_t base = LP_OFF + (size_t)(n0 + rowbase + rr) * VV;
#pragma unroll
    for (int m = 0; m < 16; ++m) out[base + (m << 6) + lane] = acc[rr][m] - lse;
    if (lane == 0) {
      argi_s[rowbase + rr] = mc;
      atomicAdd(&ws[WS_HIST + mc], mask[n0 + rowbase + rr]);
    }
  }
  __syncthreads();
  float csum = 0.f, ssum = 0.f;
  const bool has_prev = (n0 % TT) != 0;
#pragma unroll
  for (int i = 0; i < 8; ++i) {
    int q = i * TPB + tid;
    int r = q >> 6;
    int c4 = (q & 63) << 2;
    int idx = argi_s[r];
    const float4 ev = *(const float4*)&e[(size_t)idx * KD + c4];
    const float4 zv = *(const float4*)&z_s[r][c4];
    *(float4*)&out[ZQ_OFF + (size_t)(n0 + r) * KD + c4] = ev;
    float mk = mask[n0 + r];
    float dx = zv.x - ev.x, dy = zv.y - ev.y, dz2 = zv.z - ev.z, dw = zv.w - ev.w;
    csum += mk * (dx * dx + dy * dy + dz2 * dz2 + dw * dw);
    if (r > 0) {
      const float4 pv = *(const float4*)&z_s[r - 1][c4];
      float ax = zv.x - pv.x, ay = zv.y - pv.y, az = zv.z - pv.z, aw = zv.w - pv.w;
      ssum += mk * (ax * ax + ay * ay + az * az + aw * aw);
    } else if (has_prev) {
      const float4 pv = *(const float4*)&z[(size_t)(n0 - 1) * KD + c4];
      float ax = zv.x - pv.x, ay = zv.y - pv.y, az = zv.z - pv.z, aw = zv.w - pv.w;
      ssum += mk * (ax * ax + ay * ay + az * az + aw * aw);
    }
  }
#pragma unroll
  for (int d = 32; d >= 1; d >>= 1) {
    csum += __shfl_xor(csum, d);
    ssum += __shfl_xor(ssum, d);
  }
  if (lane == 0) { cred[wave] = csum; sred[wave] = ssum; }
  __syncthreads();
  if (tid == 0) {
    ws[WS_CSUM + blockIdx.x] = cred[0] + cred[1] + cred[2] + cred[3];
    ws[WS_SSUM + blockIdx.x] = sred[0] + sred[1] + sred[2] + sred[3];
    float ms = 0.f;
    for (int r2 = 0; r2 < BM; ++r2) ms += mask[n0 + r2];
    ws[WS_MSUM + blockIdx.x] = ms;
  }
}

__global__ __launch_bounds__(1024) void tok_final(const float* __restrict__ ws,
                                                  float* __restrict__ out) {
  const int t = threadIdx.x;
  const int lane = t & 63, w = t >> 6;
  __shared__ float red[16];
  auto blockReduce = [&](float v) -> float {
#pragma unroll
    for (int d = 32; d >= 1; d >>= 1) v += __shfl_xor(v, d);
    __syncthreads();
    if (lane == 0) red[w] = v;
    __syncthreads();
    float s = 0.f;
#pragma unroll
    for (int i = 0; i < 16; ++i) s += red[i];
    return s;
  };
  float Mtot = blockReduce(ws[WS_MSUM + t]);
  float Ctot = blockReduce(ws[WS_CSUM + t]);
  float Stot = blockReduce(ws[WS_SSUM + t]);
  float prob = ws[WS_HIST + t] / Mtot;
  float psum = blockReduce(prob);
  out[EM_OFF + t] = prob / psum;
  if (t == 0) {
    float vc = Mtot * (float)KD;
    out[0] = Stot / vc;  // smoothness_loss
    out[1] = Ctot / vc;  // commitment_loss
  }
}

extern "C" void kernel_launch(void* const* d_in, const int* in_sizes, int n_in,
                              void* d_out, int out_size, void* d_ws,
                              size_t ws_size, hipStream_t stream) {
  const float* z = (const float*)d_in[0];
  const float* mask = (const float*)d_in[1];
  const float* cw = (const float*)d_in[2];
  float* out = (float*)d_out;
  float* ws = (float*)d_ws;
  hipMemsetAsync(ws, 0, 1024 * sizeof(float), stream);  // histogram zeros
  if (ws_size >= (size_t)WS_NEED) {
    unsigned short* e8 = (unsigned short*)(ws + WS_E8);
    tok_prep<<<128, 256, 0, stream>>>(cw, e8);
    tok_mfma<<<NBLK, TPB2, 0, stream>>>(z, mask, cw, e8, out, ws);
  } else {
    tok_fb<<<NBLK, TPB, 0, stream>>>(z, mask, cw, out, ws);
  }
  tok_final<<<1, 1024, 0, stream>>>(ws, out);
}